// Round 1
// baseline (339.340 us; speedup 1.0000x reference)
//
#include <hip/hip_runtime.h>
#include <hip/hip_bf16.h>

// MHA: H=16, DM=1024, DK=DV=64, S=2048, B=2.  All inputs fp32; internal compute bf16 MFMA.
// ws layout (bf16 elements): q[16][2][2048][64], k[...], v[...], concat[2048][2][1024]

typedef __bf16 bf16;
typedef bf16 bf16x8 __attribute__((ext_vector_type(8)));
typedef bf16 bf16x4 __attribute__((ext_vector_type(4)));
typedef float f32x4 __attribute__((ext_vector_type(4)));

#define MFMA16(a, b, c) __builtin_amdgcn_mfma_f32_16x16x32_bf16((a), (b), (c), 0, 0, 0)

static __device__ __forceinline__ bf16x8 load8(const bf16* p) {
  return *reinterpret_cast<const bf16x8*>(p);
}
static __device__ __forceinline__ void store8(bf16* p, bf16x8 v) {
  *reinterpret_cast<bf16x8*>(p) = v;
}
static __device__ __forceinline__ bf16x8 cvt8(float4 a, float4 b) {
  bf16x8 o;
  o[0] = (bf16)a.x; o[1] = (bf16)a.y; o[2] = (bf16)a.z; o[3] = (bf16)a.w;
  o[4] = (bf16)b.x; o[5] = (bf16)b.y; o[6] = (bf16)b.z; o[7] = (bf16)b.w;
  return o;
}
static __device__ __forceinline__ f32x4 zero4() {
  f32x4 v; v[0] = 0.f; v[1] = 0.f; v[2] = 0.f; v[3] = 0.f; return v;
}

// ---------------------------------------------------------------------------
// Kernel 1: QKV projection.  C[r=(s,b)][c=(h,d)] = sum_m X[r][m] * W[h][m][d]
// out layout [H][B][S][64] bf16.  128x128x32 tiles, 4 waves, each 64x64.
// ---------------------------------------------------------------------------
__global__ __launch_bounds__(256) void proj_kernel(
    const float* __restrict__ X0, const float* __restrict__ X1, const float* __restrict__ X2,
    const float* __restrict__ W0, const float* __restrict__ W1, const float* __restrict__ W2,
    bf16* __restrict__ o0, bf16* __restrict__ o1, bf16* __restrict__ o2) {
  const int z = blockIdx.z;
  const float* X = (z == 0) ? X0 : ((z == 1) ? X1 : X2);
  const float* W = (z == 0) ? W0 : ((z == 1) ? W1 : W2);
  bf16* outp = (z == 0) ? o0 : ((z == 1) ? o1 : o2);

  const int mBase = blockIdx.y * 128;
  const int nBase = blockIdx.x * 128;

  __shared__ bf16 Al[128][40];   // [m][k], +8 pad -> only free 2-way bank aliasing
  __shared__ bf16 Bl[128][40];   // [n][k] (transposed so B-frag reads are contiguous)

  const int t = threadIdx.x;
  const int lane = t & 63;
  const int wave = t >> 6;
  const int wm = (wave >> 1) * 64;
  const int wn = (wave & 1) * 64;
  const int ln = lane & 15;
  const int quad = lane >> 4;

  f32x4 acc[4][4];
#pragma unroll
  for (int i = 0; i < 4; i++)
#pragma unroll
    for (int j = 0; j < 4; j++) acc[i][j] = zero4();

  const int ar = t >> 1;          // 0..127 (A row)
  const int ak = (t & 1) * 16;    // 0/16   (A k chunk)
  const int bm = t >> 3;          // 0..31  (B k-row)
  const int bn = (t & 7) * 16;    // 0..112 (B col chunk; stays inside one 64-wide h-block)
  const int hh = (nBase + bn) >> 6;
  const int dk0 = (nBase + bn) & 63;

  for (int k0 = 0; k0 < 1024; k0 += 32) {
    __syncthreads();
    {  // A tile: 128x32 fp32 -> bf16
      const float4* src = reinterpret_cast<const float4*>(X + (size_t)(mBase + ar) * 1024 + k0 + ak);
      float4 v0 = src[0], v1 = src[1], v2 = src[2], v3 = src[3];
      store8(&Al[ar][ak], cvt8(v0, v1));
      store8(&Al[ar][ak + 8], cvt8(v2, v3));
    }
    {  // B tile: W[h][k0+bm][dk0..dk0+15] -> Bl[n][k] transposed
      const float4* src = reinterpret_cast<const float4*>(W + (size_t)hh * 65536 + (size_t)(k0 + bm) * 64 + dk0);
      float4 v0 = src[0], v1 = src[1], v2 = src[2], v3 = src[3];
      bf16 tmp[16] = {(bf16)v0.x, (bf16)v0.y, (bf16)v0.z, (bf16)v0.w,
                      (bf16)v1.x, (bf16)v1.y, (bf16)v1.z, (bf16)v1.w,
                      (bf16)v2.x, (bf16)v2.y, (bf16)v2.z, (bf16)v2.w,
                      (bf16)v3.x, (bf16)v3.y, (bf16)v3.z, (bf16)v3.w};
#pragma unroll
      for (int i = 0; i < 16; i++) Bl[bn + i][bm] = tmp[i];
    }
    __syncthreads();

    bf16x8 a[4], bfr[4];
#pragma unroll
    for (int i = 0; i < 4; i++) a[i] = load8(&Al[wm + i * 16 + ln][quad * 8]);
#pragma unroll
    for (int j = 0; j < 4; j++) bfr[j] = load8(&Bl[wn + j * 16 + ln][quad * 8]);
#pragma unroll
    for (int i = 0; i < 4; i++)
#pragma unroll
      for (int j = 0; j < 4; j++) acc[i][j] = MFMA16(a[i], bfr[j], acc[i][j]);
  }

  // Epilogue: C/D layout row=quad*4+reg, col=ln.  Scatter to [H][B][S][64].
#pragma unroll
  for (int i = 0; i < 4; i++) {
#pragma unroll
    for (int j = 0; j < 4; j++) {
      const int c = nBase + wn + j * 16 + ln;
      const int ch = c >> 6, cd = c & 63;
#pragma unroll
      for (int r = 0; r < 4; r++) {
        const int row = mBase + wm + i * 16 + quad * 4 + r;  // row = s*2+b
        const int s = row >> 1, bb = row & 1;
        outp[((size_t)(ch * 2 + bb) * 2048 + s) * 64 + cd] = (bf16)acc[i][j][r];
      }
    }
  }
}

// ---------------------------------------------------------------------------
// Kernel 2: causal flash attention per (h,b).  Block = 64 q-rows (4 waves x 16),
// K/V tiles of 128.  Online softmax fp32; P -> per-wave LDS -> A-frags (m120).
// Writes concat [S][B][H*64] bf16.
// ---------------------------------------------------------------------------
__global__ __launch_bounds__(256) void attn_kernel(
    const bf16* __restrict__ qws, const bf16* __restrict__ kws, const bf16* __restrict__ vws,
    bf16* __restrict__ cc) {
  const int hb = blockIdx.y;  // h*2+b
  const int h = hb >> 1, b = hb & 1;
  const int q0 = blockIdx.x * 64;
  const int t = threadIdx.x;
  const int lane = t & 63;
  const int wave = t >> 6;
  const int ln = lane & 15;
  const int quad = lane >> 4;

  const bf16* qh = qws + (size_t)hb * 2048 * 64;
  const bf16* kh = kws + (size_t)hb * 2048 * 64;
  const bf16* vh = vws + (size_t)hb * 2048 * 64;

  __shared__ bf16 Kl[128][72];       // [kv][d], +8 pad
  __shared__ bf16 Vt[64][136];       // [d][kv] transposed, +8 pad
  __shared__ bf16 Pl[4][16][136];    // per-wave P, [q][kv], +8 pad

  // Q fragments (A-operand): row = q0+wave*16+ln, k = quad*8+j (+32)
  const int qrow = q0 + wave * 16 + ln;
  const bf16x8 qf0 = load8(qh + (size_t)qrow * 64 + quad * 8);
  const bf16x8 qf1 = load8(qh + (size_t)qrow * 64 + 32 + quad * 8);

  float m_r[4], l_r[4];
  f32x4 accO[4];
#pragma unroll
  for (int r = 0; r < 4; r++) { m_r[r] = -1e30f; l_r[r] = 0.f; }
#pragma unroll
  for (int d = 0; d < 4; d++) accO[d] = zero4();

  const int ntiles = ((q0 + 63) >> 7) + 1;
  const int kr = t >> 1, kc = (t & 1) * 32;       // K staging
  const int vk = (t >> 3) * 4, vd = (t & 7) * 8;  // V-transpose staging

  for (int jt = 0; jt < ntiles; jt++) {
    const int kt0 = jt * 128;
    __syncthreads();
    {  // K tile 128x64
      const bf16* src = kh + (size_t)(kt0 + kr) * 64 + kc;
      store8(&Kl[kr][kc], load8(src));
      store8(&Kl[kr][kc + 8], load8(src + 8));
      store8(&Kl[kr][kc + 16], load8(src + 16));
      store8(&Kl[kr][kc + 24], load8(src + 24));
    }
    {  // V tile transposed: thread reads 4(kv) x 8(d) block, writes 8 cols of 4
      bf16x8 r0 = load8(vh + (size_t)(kt0 + vk + 0) * 64 + vd);
      bf16x8 r1 = load8(vh + (size_t)(kt0 + vk + 1) * 64 + vd);
      bf16x8 r2 = load8(vh + (size_t)(kt0 + vk + 2) * 64 + vd);
      bf16x8 r3 = load8(vh + (size_t)(kt0 + vk + 3) * 64 + vd);
#pragma unroll
      for (int i = 0; i < 8; i++) {
        bf16x4 w;
        w[0] = r0[i]; w[1] = r1[i]; w[2] = r2[i]; w[3] = r3[i];
        *reinterpret_cast<bf16x4*>(&Vt[vd + i][vk]) = w;
      }
    }
    __syncthreads();

    // S = Q K^T (scaled), per wave 16 q-rows x 128 keys
    float sv[8][4];
#pragma unroll
    for (int nt = 0; nt < 8; nt++) {
      f32x4 s = zero4();
      bf16x8 b0 = load8(&Kl[nt * 16 + ln][quad * 8]);
      bf16x8 b1 = load8(&Kl[nt * 16 + ln][32 + quad * 8]);
      s = MFMA16(qf0, b0, s);
      s = MFMA16(qf1, b1, s);
#pragma unroll
      for (int r = 0; r < 4; r++) sv[nt][r] = s[r] * 0.125f;  // 1/sqrt(64)
    }
    if (kt0 + 127 > q0) {  // only boundary tiles need masking
#pragma unroll
      for (int nt = 0; nt < 8; nt++) {
        const int kg = kt0 + nt * 16 + ln;
#pragma unroll
        for (int r = 0; r < 4; r++) {
          const int qg = q0 + wave * 16 + quad * 4 + r;
          if (kg > qg) sv[nt][r] = -1e30f;
        }
      }
    }
    // online softmax per q-row (rows live in 16-lane groups; xor-shuffle <16 stays in group)
#pragma unroll
    for (int r = 0; r < 4; r++) {
      float rm = sv[0][r];
#pragma unroll
      for (int nt = 1; nt < 8; nt++) rm = fmaxf(rm, sv[nt][r]);
      rm = fmaxf(rm, __shfl_xor(rm, 8));
      rm = fmaxf(rm, __shfl_xor(rm, 4));
      rm = fmaxf(rm, __shfl_xor(rm, 2));
      rm = fmaxf(rm, __shfl_xor(rm, 1));
      const float mnew = fmaxf(m_r[r], rm);
      const float alpha = __expf(m_r[r] - mnew);
      float rs = 0.f;
#pragma unroll
      for (int nt = 0; nt < 8; nt++) {
        const float p = __expf(sv[nt][r] - mnew);
        sv[nt][r] = p;
        rs += p;
      }
      rs += __shfl_xor(rs, 8);
      rs += __shfl_xor(rs, 4);
      rs += __shfl_xor(rs, 2);
      rs += __shfl_xor(rs, 1);
      l_r[r] = l_r[r] * alpha + rs;
      m_r[r] = mnew;
#pragma unroll
      for (int d = 0; d < 4; d++) accO[d][r] *= alpha;
    }
    // P: C-layout -> LDS -> A-layout (per-wave region)
#pragma unroll
    for (int nt = 0; nt < 8; nt++)
#pragma unroll
      for (int r = 0; r < 4; r++) Pl[wave][quad * 4 + r][nt * 16 + ln] = (bf16)sv[nt][r];
    __syncthreads();  // also guarantees P visibility; cheap vs. MFMA work
    // O += P V
#pragma unroll
    for (int ks = 0; ks < 4; ks++) {
      bf16x8 pa = load8(&Pl[wave][ln][ks * 32 + quad * 8]);
#pragma unroll
      for (int d = 0; d < 4; d++) {
        bf16x8 vb = load8(&Vt[d * 16 + ln][ks * 32 + quad * 8]);
        accO[d] = MFMA16(pa, vb, accO[d]);
      }
    }
  }

  // epilogue: O /= l, write concat[s][b][h*64+d]
#pragma unroll
  for (int r = 0; r < 4; r++) {
    const float inv = 1.0f / l_r[r];
    const int srow = q0 + wave * 16 + quad * 4 + r;
#pragma unroll
    for (int d = 0; d < 4; d++) {
      cc[((size_t)srow * 2 + b) * 1024 + h * 64 + d * 16 + ln] = (bf16)(accO[d][r] * inv);
    }
  }
}

// ---------------------------------------------------------------------------
// Kernel 3: output projection. out[r=(s,b)][n] = sum_k concat[r][k]*WO[k][n], fp32 out.
// ---------------------------------------------------------------------------
__global__ __launch_bounds__(256) void out_kernel(
    const bf16* __restrict__ A, const float* __restrict__ WOp, float* __restrict__ out) {
  const int mBase = blockIdx.y * 128;
  const int nBase = blockIdx.x * 128;

  __shared__ bf16 Al[128][40];
  __shared__ bf16 Bl[128][40];

  const int t = threadIdx.x;
  const int lane = t & 63;
  const int wave = t >> 6;
  const int wm = (wave >> 1) * 64;
  const int wn = (wave & 1) * 64;
  const int ln = lane & 15;
  const int quad = lane >> 4;

  f32x4 acc[4][4];
#pragma unroll
  for (int i = 0; i < 4; i++)
#pragma unroll
    for (int j = 0; j < 4; j++) acc[i][j] = zero4();

  const int ar = t >> 1;
  const int ak = (t & 1) * 16;
  const int bm = t >> 3;
  const int bn = (t & 7) * 16;

  for (int k0 = 0; k0 < 1024; k0 += 32) {
    __syncthreads();
    {  // A tile already bf16
      const bf16* src = A + (size_t)(mBase + ar) * 1024 + k0 + ak;
      store8(&Al[ar][ak], load8(src));
      store8(&Al[ar][ak + 8], load8(src + 8));
    }
    {  // B tile: WO fp32 -> bf16 transposed
      const float4* src = reinterpret_cast<const float4*>(WOp + (size_t)(k0 + bm) * 1024 + nBase + bn);
      float4 v0 = src[0], v1 = src[1], v2 = src[2], v3 = src[3];
      bf16 tmp[16] = {(bf16)v0.x, (bf16)v0.y, (bf16)v0.z, (bf16)v0.w,
                      (bf16)v1.x, (bf16)v1.y, (bf16)v1.z, (bf16)v1.w,
                      (bf16)v2.x, (bf16)v2.y, (bf16)v2.z, (bf16)v2.w,
                      (bf16)v3.x, (bf16)v3.y, (bf16)v3.z, (bf16)v3.w};
#pragma unroll
      for (int i = 0; i < 16; i++) Bl[bn + i][bm] = tmp[i];
    }
    __syncthreads();

    bf16x8 a[4], bfr[4];
#pragma unroll
    for (int i = 0; i < 4; i++) a[i] = load8(&Al[wm + i * 16 + ln][quad * 8]);
#pragma unroll
    for (int j = 0; j < 4; j++) bfr[j] = load8(&Bl[wn + j * 16 + ln][quad * 8]);
#pragma unroll
    for (int i = 0; i < 4; i++)
#pragma unroll
      for (int j = 0; j < 4; j++) acc[i][j] = MFMA16(a[i], bfr[j], acc[i][j]);
  }

#pragma unroll
  for (int i = 0; i < 4; i++)
#pragma unroll
    for (int j = 0; j < 4; j++)
#pragma unroll
      for (int r = 0; r < 4; r++)
        out[(size_t)(mBase + wm + i * 16 + quad * 4 + r) * 1024 + nBase + wn + j * 16 + ln] =
            acc[i][j][r];
}

extern "C" void kernel_launch(void* const* d_in, const int* in_sizes, int n_in,
                              void* d_out, int out_size, void* d_ws, size_t ws_size,
                              hipStream_t stream) {
  (void)in_sizes; (void)n_in; (void)out_size; (void)ws_size;
  const float* Q  = (const float*)d_in[0];
  const float* K  = (const float*)d_in[1];
  const float* V  = (const float*)d_in[2];
  const float* WQ = (const float*)d_in[3];
  const float* WK = (const float*)d_in[4];
  const float* WV = (const float*)d_in[5];
  const float* WO = (const float*)d_in[6];
  float* out = (float*)d_out;

  const size_t per = (size_t)16 * 2 * 2048 * 64;  // 4,194,304 bf16 elements
  bf16* qws = (bf16*)d_ws;
  bf16* kws = qws + per;
  bf16* vws = kws + per;
  bf16* cc  = vws + per;  // [2048][2][1024]

  proj_kernel<<<dim3(8, 32, 3), 256, 0, stream>>>(Q, K, V, WQ, WK, WV, qws, kws, vws);
  attn_kernel<<<dim3(32, 32), 256, 0, stream>>>(qws, kws, vws, cc);
  out_kernel<<<dim3(8, 32), 256, 0, stream>>>(cc, WO, out);
}

// Round 2
// 260.337 us; speedup vs baseline: 1.3035x; 1.3035x over previous
//
#include <hip/hip_runtime.h>
#include <hip/hip_bf16.h>

// MHA: H=16, DM=1024, DK=DV=64, S=2048, B=2. fp32 in/out, bf16 MFMA internals.
// ws (32MB): [0,8MB): Wt (3x2MB, dead after proj) -> reused as cc [4096][1024] bf16
//            [8,16MB): qws [hb][s][64] -> reused as WOt [n][k] after attn
//            [16,24MB): kws [hb][s][64]
//            [24,32MB): vtws [hb][d][pos] (transposed+nt-permuted V)

typedef __bf16 bf16;
typedef bf16 bf16x8 __attribute__((ext_vector_type(8)));
typedef float f32x4 __attribute__((ext_vector_type(4)));

#define MFMA16(a, b, c) __builtin_amdgcn_mfma_f32_16x16x32_bf16((a), (b), (c), 0, 0, 0)

static __device__ __forceinline__ bf16x8 load8(const bf16* p) {
  return *reinterpret_cast<const bf16x8*>(p);
}
static __device__ __forceinline__ void store8(bf16* p, bf16x8 v) {
  *reinterpret_cast<bf16x8*>(p) = v;
}
static __device__ __forceinline__ bf16x8 cvt8(float4 a, float4 b) {
  bf16x8 o;
  o[0] = (bf16)a.x; o[1] = (bf16)a.y; o[2] = (bf16)a.z; o[3] = (bf16)a.w;
  o[4] = (bf16)b.x; o[5] = (bf16)b.y; o[6] = (bf16)b.z; o[7] = (bf16)b.w;
  return o;
}
static __device__ __forceinline__ f32x4 zero4() {
  f32x4 v; v[0] = 0.f; v[1] = 0.f; v[2] = 0.f; v[3] = 0.f; return v;
}
// async global->LDS, 16B per lane; lds base wave-uniform (HW scatters lane*16)
static __device__ __forceinline__ void gload_lds16(const bf16* g, bf16* l) {
  __builtin_amdgcn_global_load_lds(
      (const __attribute__((address_space(1))) void*)g,
      (__attribute__((address_space(3))) void*)l, 16, 0, 0);
}

// ---------------------------------------------------------------------------
// K0: transpose + fp32->bf16 convert (+scale). in[z][R][C] -> out[z*C + c][r].
// ---------------------------------------------------------------------------
__global__ __launch_bounds__(256) void tcvt_kernel(const float* __restrict__ in,
                                                   bf16* __restrict__ out,
                                                   int R, int C, float scale) {
  __shared__ float tile[32][33];
  const int r0 = blockIdx.y * 32, c0 = blockIdx.x * 32;
  in += (size_t)blockIdx.z * R * C;
  out += (size_t)blockIdx.z * R * C;
  const int tx = threadIdx.x & 31, ty = threadIdx.x >> 5;
#pragma unroll
  for (int i = 0; i < 32; i += 8) tile[ty + i][tx] = in[(size_t)(r0 + ty + i) * C + c0 + tx];
  __syncthreads();
#pragma unroll
  for (int i = 0; i < 32; i += 8)
    out[(size_t)(c0 + ty + i) * R + r0 + tx] = (bf16)(tile[tx][ty + i] * scale);
}

// ---------------------------------------------------------------------------
// K1: QKV projection. C[r=(s,b)][n=(h,d)] = sum_m X[r][m] * Wt[n][m].
// A: manual fp32->bf16 staging (padded LDS). B: swizzled global_load_lds (bf16).
// z=0 -> qws [hb][s][64] (scale folded in Wt), z=1 -> kws, z=2 -> vtws permuted.
// ---------------------------------------------------------------------------
__global__ __launch_bounds__(256) void proj_kernel(
    const float* __restrict__ X0, const float* __restrict__ X1, const float* __restrict__ X2,
    const bf16* __restrict__ Wt, bf16* __restrict__ qws, bf16* __restrict__ kws,
    bf16* __restrict__ vtws) {
  const int z = blockIdx.z;
  const float* X = (z == 0) ? X0 : ((z == 1) ? X1 : X2);
  const bf16* Wz = Wt + (size_t)z * 1024 * 1024;

  const int mBase = blockIdx.y * 128;
  const int nBase = blockIdx.x * 128;

  __shared__ bf16 Al[128][40];   // padded: conflict-free frag reads
  __shared__ bf16 Bl[128 * 32];  // swizzled, unpadded (async staging)

  const int t = threadIdx.x;
  const int lane = t & 63;
  const int wave = t >> 6;
  const int wm = (wave >> 1) * 64;
  const int wn = (wave & 1) * 64;
  const int ln = lane & 15;
  const int quad = lane >> 4;
  const int bswz = quad ^ ((ln >> 1) & 3);  // P=4 chunk swizzle (lane-const)

  f32x4 acc[4][4];
#pragma unroll
  for (int i = 0; i < 4; i++)
#pragma unroll
    for (int j = 0; j < 4; j++) acc[i][j] = zero4();

  const int ar = t >> 1;
  const int ak = (t & 1) * 16;

  for (int k0 = 0; k0 < 1024; k0 += 32) {
    __syncthreads();
    // B tile: 128n x 32k bf16 = 512 chunks, async with XOR swizzle q' = q ^ ((m>>1)&3)
#pragma unroll
    for (int i = 0; i < 2; i++) {
      const int c = i * 256 + t;
      const int mp = c >> 2;
      const int ql = (c & 3) ^ ((mp >> 1) & 3);
      gload_lds16(Wz + (size_t)(nBase + mp) * 1024 + k0 + ql * 8,
                  Bl + (size_t)(i * 256 + wave * 64) * 8);
    }
    // A tile: 128m x 32k fp32 -> bf16
    {
      const float4* src = reinterpret_cast<const float4*>(X + (size_t)(mBase + ar) * 1024 + k0 + ak);
      float4 v0 = src[0], v1 = src[1], v2 = src[2], v3 = src[3];
      store8(&Al[ar][ak], cvt8(v0, v1));
      store8(&Al[ar][ak + 8], cvt8(v2, v3));
    }
    __syncthreads();

    bf16x8 a[4], bfr[4];
#pragma unroll
    for (int i = 0; i < 4; i++) a[i] = load8(&Al[wm + i * 16 + ln][quad * 8]);
#pragma unroll
    for (int j = 0; j < 4; j++) {
      const int n = wn + j * 16 + ln;
      bfr[j] = load8(Bl + (size_t)(n * 4 + bswz) * 8);
    }
#pragma unroll
    for (int i = 0; i < 4; i++)
#pragma unroll
      for (int j = 0; j < 4; j++) acc[i][j] = MFMA16(a[i], bfr[j], acc[i][j]);
  }

  // Epilogue: C/D row=quad*4+r, col=ln
#pragma unroll
  for (int i = 0; i < 4; i++) {
#pragma unroll
    for (int j = 0; j < 4; j++) {
      const int col = nBase + wn + j * 16 + ln;
      const int h = col >> 6, d = col & 63;
#pragma unroll
      for (int r = 0; r < 4; r++) {
        const int row = mBase + wm + i * 16 + quad * 4 + r;  // row = s*2+b
        const int s = row >> 1, bb = row & 1;
        const int hb = h * 2 + bb;
        const bf16 val = (bf16)acc[i][j][r];
        if (z == 0) {
          qws[((size_t)hb * 2048 + s) * 64 + d] = val;
        } else if (z == 1) {
          kws[((size_t)hb * 2048 + s) * 64 + d] = val;
        } else {
          // permuted pos: kv=s&127 -> p = (kv&15)*8 + ((kv>>4)&7)
          const int pos = ((s >> 7) << 7) + ((s & 15) << 3) + ((s >> 4) & 7);
          vtws[((size_t)hb * 64 + d) * 2048 + pos] = val;
        }
      }
    }
  }
}

// ---------------------------------------------------------------------------
// K2: causal flash attention. Block = (hb, 128 q-rows), 4 waves x 32 rows.
// KV tile 128, async swizzled staging, no-max softmax (scale pre-folded into Q),
// l via ones-MFMA, P through swizzled per-wave LDS (nt-permuted cols).
// ---------------------------------------------------------------------------
__global__ __launch_bounds__(256) void attn_kernel(
    const bf16* __restrict__ qws, const bf16* __restrict__ kws, const bf16* __restrict__ vtws,
    bf16* __restrict__ cc) {
  // complementary (j, j+256) q-tile mapping for causal load balance
  const int j = blockIdx.x;
  int qb, hb;
  if (j < 256) { qb = j & 15; hb = j >> 4; }
  else         { qb = 15 - (j & 15); hb = 16 + ((j - 256) >> 4); }
  const int q0 = qb * 128;
  const int h = hb >> 1, b = hb & 1;

  const int t = threadIdx.x;
  const int lane = t & 63;
  const int wave = t >> 6;
  const int ln = lane & 15;
  const int quad = lane >> 4;
  const int swz3 = ln & 7;

  const bf16* qh = qws + (size_t)hb * 2048 * 64;
  const bf16* kh = kws + (size_t)hb * 2048 * 64;
  const bf16* vh = vtws + (size_t)hb * 64 * 2048;

  __shared__ bf16 Kl[128 * 64];      // swizzled [kv][64]
  __shared__ bf16 Vl[64 * 128];      // swizzled [d][p]
  __shared__ bf16 Pl[4 * 32 * 128];  // per-wave, swizzled [q][p]
  bf16* Plw = Pl + (size_t)wave * 32 * 128;

  // Q A-frags: rows q0+wave*32+mb*16+ln, k = hh*32+quad*8+j
  bf16x8 qf[2][2];
#pragma unroll
  for (int mb = 0; mb < 2; mb++)
#pragma unroll
    for (int hh = 0; hh < 2; hh++)
      qf[mb][hh] = load8(qh + (size_t)(q0 + wave * 32 + mb * 16 + ln) * 64 + hh * 32 + quad * 8);

  f32x4 accO[2][4];
  f32x4 accL[2];
#pragma unroll
  for (int mb = 0; mb < 2; mb++) {
    accL[mb] = zero4();
#pragma unroll
    for (int d = 0; d < 4; d++) accO[mb][d] = zero4();
  }
  bf16x8 ones;
#pragma unroll
  for (int i = 0; i < 8; i++) ones[i] = (bf16)1.0f;

  const int ntile = qb + 1;
  for (int jt = 0; jt < ntile; jt++) {
    const int kt0 = jt * 128;
    __syncthreads();
    // K: 128 rows x 8 chunks, swizzle q' = q ^ (m&7)
#pragma unroll
    for (int i = 0; i < 4; i++) {
      const int c = i * 256 + t;
      const int mp = c >> 3;
      const int ql = (c & 7) ^ (mp & 7);
      gload_lds16(kh + (size_t)(kt0 + mp) * 64 + ql * 8, Kl + (size_t)(i * 256 + wave * 64) * 8);
    }
    // V: 64 rows x 16 chunks (pre-permuted in global), swizzle q' = q ^ (d&7)
#pragma unroll
    for (int i = 0; i < 4; i++) {
      const int c = i * 256 + t;
      const int dp = c >> 4;
      const int ql = (c & 15) ^ (dp & 7);
      gload_lds16(vh + (size_t)dp * 2048 + kt0 + ql * 8, Vl + (size_t)(i * 256 + wave * 64) * 8);
    }
    __syncthreads();

    // S = Q K^T (scale folded into Q at projection)
    f32x4 sv[2][8];
#pragma unroll
    for (int nt = 0; nt < 8; nt++) {
      const int m = nt * 16 + ln;
      bf16x8 b0 = load8(Kl + (size_t)(m * 8 + (quad ^ swz3)) * 8);
      bf16x8 b1 = load8(Kl + (size_t)(m * 8 + ((quad + 4) ^ swz3)) * 8);
#pragma unroll
      for (int mb = 0; mb < 2; mb++) {
        f32x4 s = MFMA16(qf[mb][0], b0, zero4());
        s = MFMA16(qf[mb][1], b1, s);
        sv[mb][nt] = s;
      }
    }
    if (jt == qb) {  // diagonal tile: causal mask
#pragma unroll
      for (int mb = 0; mb < 2; mb++)
#pragma unroll
        for (int nt = 0; nt < 8; nt++) {
          const int kg = kt0 + nt * 16 + ln;
#pragma unroll
          for (int r = 0; r < 4; r++) {
            const int qg = q0 + wave * 32 + mb * 16 + quad * 4 + r;
            if (kg > qg) sv[mb][nt][r] = -1e30f;
          }
        }
    }
    // P = exp(S), write per-wave swizzled LDS (b128; cols nt-permuted p=ln*8+nt)
#pragma unroll
    for (int mb = 0; mb < 2; mb++) {
#pragma unroll
      for (int r = 0; r < 4; r++) {
        const int row = mb * 16 + quad * 4 + r;
        bf16x8 pw;
#pragma unroll
        for (int nt = 0; nt < 8; nt++) pw[nt] = (bf16)__expf(sv[mb][nt][r]);
        store8(Plw + (size_t)(row * 16 + (ln ^ (row & 7))) * 8, pw);
      }
    }
    // O += P V ; l += P * 1  (same-wave LDS RAW: compiler orders via lgkmcnt)
#pragma unroll
    for (int ks = 0; ks < 4; ks++) {
      bf16x8 pa[2];
#pragma unroll
      for (int mb = 0; mb < 2; mb++) {
        const int row = mb * 16 + ln;
        pa[mb] = load8(Plw + (size_t)(row * 16 + ((ks * 4 + quad) ^ (ln & 7))) * 8);
      }
#pragma unroll
      for (int d = 0; d < 4; d++) {
        const int drow = d * 16 + ln;
        bf16x8 vb = load8(Vl + (size_t)(drow * 16 + ((ks * 4 + quad) ^ swz3)) * 8);
#pragma unroll
        for (int mb = 0; mb < 2; mb++) accO[mb][d] = MFMA16(pa[mb], vb, accO[mb][d]);
      }
#pragma unroll
      for (int mb = 0; mb < 2; mb++) accL[mb] = MFMA16(pa[mb], ones, accL[mb]);
    }
  }

  // epilogue: O /= l, write concat [s*2+b][h*64+...]
#pragma unroll
  for (int mb = 0; mb < 2; mb++) {
#pragma unroll
    for (int r = 0; r < 4; r++) {
      const float inv = 1.0f / accL[mb][r];
      const int s = q0 + wave * 32 + mb * 16 + quad * 4 + r;
#pragma unroll
      for (int d = 0; d < 4; d++)
        cc[((size_t)s * 2 + b) * 1024 + h * 64 + d * 16 + ln] = (bf16)(accO[mb][d][r] * inv);
    }
  }
}

// ---------------------------------------------------------------------------
// K3: output projection. out[r][n] = sum_k cc[r][k] * WOt[n][k], fp32 out.
// Both operands bf16, fully async-staged with swizzle. Tile 64m x 128n.
// ---------------------------------------------------------------------------
__global__ __launch_bounds__(256) void out_kernel(
    const bf16* __restrict__ A, const bf16* __restrict__ Bt, float* __restrict__ outp) {
  const int mBase = blockIdx.y * 64;
  const int nBase = blockIdx.x * 128;

  __shared__ bf16 Al[64 * 32];
  __shared__ bf16 Bl[128 * 32];

  const int t = threadIdx.x;
  const int lane = t & 63;
  const int wave = t >> 6;
  const int wm = (wave >> 1) * 32;
  const int wn = (wave & 1) * 64;
  const int ln = lane & 15;
  const int quad = lane >> 4;
  const int bswz = quad ^ ((ln >> 1) & 3);

  f32x4 acc[2][4];
#pragma unroll
  for (int i = 0; i < 2; i++)
#pragma unroll
    for (int j = 0; j < 4; j++) acc[i][j] = zero4();

  for (int k0 = 0; k0 < 1024; k0 += 32) {
    __syncthreads();
    {  // A: 64x32 = 256 chunks (1 instr)
      const int mp = t >> 2;
      const int ql = (t & 3) ^ ((mp >> 1) & 3);
      gload_lds16(A + (size_t)(mBase + mp) * 1024 + k0 + ql * 8, Al + (size_t)(wave * 64) * 8);
    }
#pragma unroll
    for (int i = 0; i < 2; i++) {  // B: 128x32 = 512 chunks
      const int c = i * 256 + t;
      const int mp = c >> 2;
      const int ql = (c & 3) ^ ((mp >> 1) & 3);
      gload_lds16(Bt + (size_t)(nBase + mp) * 1024 + k0 + ql * 8,
                  Bl + (size_t)(i * 256 + wave * 64) * 8);
    }
    __syncthreads();

    bf16x8 a[2], bfr[4];
#pragma unroll
    for (int i = 0; i < 2; i++) {
      const int m = wm + i * 16 + ln;
      a[i] = load8(Al + (size_t)(m * 4 + bswz) * 8);
    }
#pragma unroll
    for (int jj = 0; jj < 4; jj++) {
      const int n = wn + jj * 16 + ln;
      bfr[jj] = load8(Bl + (size_t)(n * 4 + bswz) * 8);
    }
#pragma unroll
    for (int i = 0; i < 2; i++)
#pragma unroll
      for (int jj = 0; jj < 4; jj++) acc[i][jj] = MFMA16(a[i], bfr[jj], acc[i][jj]);
  }

#pragma unroll
  for (int i = 0; i < 2; i++)
#pragma unroll
    for (int jj = 0; jj < 4; jj++)
#pragma unroll
      for (int r = 0; r < 4; r++)
        outp[(size_t)(mBase + wm + i * 16 + quad * 4 + r) * 1024 + nBase + wn + jj * 16 + ln] =
            acc[i][jj][r];
}

extern "C" void kernel_launch(void* const* d_in, const int* in_sizes, int n_in,
                              void* d_out, int out_size, void* d_ws, size_t ws_size,
                              hipStream_t stream) {
  (void)in_sizes; (void)n_in; (void)out_size; (void)ws_size;
  const float* Q  = (const float*)d_in[0];
  const float* K  = (const float*)d_in[1];
  const float* V  = (const float*)d_in[2];
  const float* WQ = (const float*)d_in[3];
  const float* WK = (const float*)d_in[4];
  const float* WV = (const float*)d_in[5];
  const float* WO = (const float*)d_in[6];
  float* outp = (float*)d_out;

  const size_t REG = (size_t)4 * 1024 * 1024;  // 4M bf16 elems = 8MB per region
  bf16* base = (bf16*)d_ws;
  bf16* Wt   = base;            // 3M elems, dead after proj
  bf16* cc   = base;            // [4096][1024], written by attn
  bf16* qws  = base + REG;      // dead after attn
  bf16* WOt  = base + REG;      // 1M elems, written after attn
  bf16* kws  = base + 2 * REG;
  bf16* vtws = base + 3 * REG;

  // weights: transpose+convert (WQ scaled by 1/sqrt(DK)=0.125)
  tcvt_kernel<<<dim3(2, 32, 16), 256, 0, stream>>>(WQ, Wt, 1024, 64, 0.125f);
  tcvt_kernel<<<dim3(2, 32, 16), 256, 0, stream>>>(WK, Wt + 1024 * 1024, 1024, 64, 1.0f);
  tcvt_kernel<<<dim3(2, 32, 16), 256, 0, stream>>>(WV, Wt + 2 * 1024 * 1024, 1024, 64, 1.0f);

  proj_kernel<<<dim3(8, 32, 3), 256, 0, stream>>>(Q, K, V, Wt, qws, kws, vtws);
  attn_kernel<<<dim3(512), 256, 0, stream>>>(qws, kws, vtws, cc);
  tcvt_kernel<<<dim3(32, 32, 1), 256, 0, stream>>>(WO, WOt, 1024, 1024, 1.0f);
  out_kernel<<<dim3(8, 64), 256, 0, stream>>>(cc, WOt, outp);
}